// Round 4
// baseline (245.106 us; speedup 1.0000x reference)
//
#include <hip/hip_runtime.h>
#include <cstdint>
#include <cstddef>

typedef unsigned short u16;
typedef unsigned int   u32;
typedef __bf16 bf16x8 __attribute__((ext_vector_type(8)));
typedef float  f32x4  __attribute__((ext_vector_type(4)));
typedef float  f32x16 __attribute__((ext_vector_type(16)));
typedef u16    u16x8  __attribute__((ext_vector_type(8)));
typedef u16    u16x4  __attribute__((ext_vector_type(4)));
typedef u32    u32x2  __attribute__((ext_vector_type(2)));
typedef u32    u32x4  __attribute__((ext_vector_type(4)));

#define DI __device__ __forceinline__

constexpr int SEQ = 4096;
constexpr int DIM = 512;
constexpr int NH  = 8;
constexpr int HD  = 64;
// scale * log2(e): softmax in exp2 domain; folded into Q at GEMM-0 epilogue
constexpr float ATT_C1 = 0.125f * 1.44269504088896340736f;

DI u16 f2bf(float f) {   // round-half-up (<=1 ulp vs RNE)
  return (u16)((__builtin_bit_cast(u32, f) + 0x8000u) >> 16);
}

// pack two fp32 -> u32 of two bf16 (round-half-up): 2 adds + 1 v_perm
DI u32 pk2(float hi, float lo) {
  u32 uh = __builtin_bit_cast(u32, hi) + 0x8000u;
  u32 ul = __builtin_bit_cast(u32, lo) + 0x8000u;
  return __builtin_amdgcn_perm(uh, ul, 0x07060302u);
}

DI float bf2f(u16 v) { return __builtin_bit_cast(float, (u32)v << 16); }

// ---------------------------------------------------------------------------
// Kernel 0: one-shot W fp32 -> bf16 (all four matrices into Wb[4][512][512])
// ---------------------------------------------------------------------------
__global__ __launch_bounds__(256) void wconv_kernel(
    const float* __restrict__ wq, const float* __restrict__ wk,
    const float* __restrict__ wv, const float* __restrict__ wfc,
    u16* __restrict__ Wb)
{
  const int idx  = blockIdx.x * 256 + threadIdx.x;
  const int base = idx * 8;
  const int mat  = base >> 18;
  const int off  = base & (512 * 512 - 1);
  const float* src = (mat == 0) ? wq : (mat == 1) ? wk : (mat == 2) ? wv : wfc;
  const float4 a = *(const float4*)(src + off);
  const float4 b = *(const float4*)(src + off + 4);
  u32x4 o = { pk2(a.y, a.x), pk2(a.w, a.z), pk2(b.y, b.x), pk2(b.w, b.z) };
  *(u32x4*)(Wb + base) = o;
}

// ---------------------------------------------------------------------------
// Kernel 1: LayerNorm (fp32) + cast to bf16.  One wave per row (64 lanes x 8).
// ---------------------------------------------------------------------------
__global__ __launch_bounds__(256) void ln_cast_kernel(
    const float* __restrict__ x, const float* __restrict__ gamma,
    const float* __restrict__ beta, u16* __restrict__ xn)
{
  const int row  = blockIdx.x * 4 + (threadIdx.x >> 6);
  const int lane = threadIdx.x & 63;
  const float* xr = x + (size_t)row * DIM + lane * 8;
  const float4 a = *(const float4*)xr;
  const float4 b = *(const float4*)(xr + 4);
  float s = a.x + a.y + a.z + a.w + b.x + b.y + b.z + b.w;
  float q = a.x*a.x + a.y*a.y + a.z*a.z + a.w*a.w
          + b.x*b.x + b.y*b.y + b.z*b.z + b.w*b.w;
#pragma unroll
  for (int m = 1; m < 64; m <<= 1) {
    s += __shfl_xor(s, m, 64);
    q += __shfl_xor(q, m, 64);
  }
  const float mu = s * (1.0f / DIM);
  const float rs = rsqrtf(q * (1.0f / DIM) - mu * mu + 1e-5f);
  const float4 g0 = *(const float4*)(gamma + lane * 8);
  const float4 g1 = *(const float4*)(gamma + lane * 8 + 4);
  const float4 e0 = *(const float4*)(beta + lane * 8);
  const float4 e1 = *(const float4*)(beta + lane * 8 + 4);
  const float v0 = (a.x - mu) * rs * g0.x + e0.x;
  const float v1 = (a.y - mu) * rs * g0.y + e0.y;
  const float v2 = (a.z - mu) * rs * g0.z + e0.z;
  const float v3 = (a.w - mu) * rs * g0.w + e0.w;
  const float v4 = (b.x - mu) * rs * g1.x + e1.x;
  const float v5 = (b.y - mu) * rs * g1.y + e1.y;
  const float v6 = (b.z - mu) * rs * g1.z + e1.z;
  const float v7 = (b.w - mu) * rs * g1.w + e1.w;
  u32x4 o = { pk2(v1, v0), pk2(v3, v2), pk2(v5, v4), pk2(v7, v6) };
  *(u32x4*)(xn + (size_t)row * DIM + lane * 8) = o;
}

// ---------------------------------------------------------------------------
// Kernel 2/4: 128x128x(BK=64) bf16 MFMA GEMM, C = A @ W^T (W pre-bf16).
//   MODE 0: N=1536 fused QKV; Q pre-scaled by ATT_C1.
//     Epilogue routes C through LDS (reusing the staging buffers) so all
//     global stores are coalesced 16B: Q,K -> [b,h,s,d], V -> Vt[b,h,d,s].
//   MODE 1: N=512; fp32 row-major output (already coalesced).
// ---------------------------------------------------------------------------
template<int MODE>
__global__ __launch_bounds__(256, 2) void gemm_kernel(
    const u16* __restrict__ A, const u16* __restrict__ Wb,
    u16* __restrict__ Qo, u16* __restrict__ Ko, u16* __restrict__ Vt,
    float* __restrict__ Co)
{
  __shared__ u16 SH[2][128][72];   // As=SH[0], Bs=SH[1]; epilogue reuses flat
  const int m0 = blockIdx.y * 128, n0 = blockIdx.x * 128;
  const int t = threadIdx.x, wave = t >> 6, lane = t & 63;
  const int quad = lane >> 4, l15 = lane & 15;
  const int wm = wave >> 1, wn = wave & 1;
  const u16* Wsrc;
  if (MODE == 0) {
    const int mat = n0 >> 9;
    Wsrc = Wb + (size_t)mat * 512 * 512 + (size_t)(n0 & 511) * DIM;
  } else {
    Wsrc = Wb + (size_t)3 * 512 * 512 + (size_t)n0 * DIM;
  }

  f32x4 acc[4][4];
#pragma unroll
  for (int i = 0; i < 4; i++)
#pragma unroll
    for (int j = 0; j < 4; j++)
#pragma unroll
      for (int r = 0; r < 4; r++) acc[i][j][r] = 0.0f;

  for (int kk = 0; kk < DIM; kk += 64) {
    __syncthreads();
#pragma unroll
    for (int it = 0; it < 4; it++) {
      const int c4 = t + it * 256;
      const int r = c4 >> 3, off = (c4 & 7) * 8;
      *(u16x8*)&SH[0][r][off] =
          *(const u16x8*)(A + (size_t)(m0 + r) * DIM + kk + off);
      *(u16x8*)&SH[1][r][off] =
          *(const u16x8*)(Wsrc + (size_t)r * DIM + kk + off);
    }
    __syncthreads();
#pragma unroll
    for (int kx = 0; kx < 2; kx++) {
      bf16x8 af[4], bfr[4];
#pragma unroll
      for (int i = 0; i < 4; i++)
        af[i] = *(const bf16x8*)&SH[0][wm * 64 + i * 16 + l15][kx * 32 + quad * 8];
#pragma unroll
      for (int j = 0; j < 4; j++)
        bfr[j] = *(const bf16x8*)&SH[1][wn * 64 + j * 16 + l15][kx * 32 + quad * 8];
#pragma unroll
      for (int i = 0; i < 4; i++)
#pragma unroll
        for (int j = 0; j < 4; j++)
          acc[i][j] = __builtin_amdgcn_mfma_f32_16x16x32_bf16(
              af[i], bfr[j], acc[i][j], 0, 0, 0);
    }
  }

  if (MODE == 1) {
#pragma unroll
    for (int i = 0; i < 4; i++) {
      const int m = m0 + wm * 64 + i * 16 + quad * 4;
#pragma unroll
      for (int j = 0; j < 4; j++) {
        const int n = n0 + wn * 64 + j * 16 + l15;
#pragma unroll
        for (int r = 0; r < 4; r++)
          Co[(size_t)(m + r) * DIM + n] = acc[i][j][r];
      }
    }
    return;
  }

  // ---- MODE 0 epilogue: LDS re-layout, coalesced stores ----
  u16* SH2 = (u16*)SH;               // flat [128][144] view
  const int mat = n0 >> 9;
  __syncthreads();                    // all MFMA reads of SH done
  if (mat < 2) {
    const float qs = (mat == 0) ? ATT_C1 : 1.0f;
    // phase A: C -> SH2[m][n] bf16 (scalar b16 LDS writes)
#pragma unroll
    for (int i = 0; i < 4; i++) {
      const int mb = wm * 64 + i * 16 + quad * 4;
#pragma unroll
      for (int j = 0; j < 4; j++) {
        const int nn = wn * 64 + j * 16 + l15;
#pragma unroll
        for (int r = 0; r < 4; r++)
          SH2[(mb + r) * 144 + nn] = f2bf(acc[i][j][r] * qs);
      }
    }
    __syncthreads();
    // phase B: coalesced 16B stores to Q/K [b,h,s,d]
    const int mloc = t >> 1, nh = (t & 1) * 64;
    const int sg = m0 + mloc, b = sg >> 12, sl = sg & 4095;
    const int ng0 = (n0 & 511) + nh, h = ng0 >> 6;
    u16* dst = (mat == 0 ? Qo : Ko) +
               ((size_t)(b * NH + h) * SEQ + sl) * HD;
#pragma unroll
    for (int k = 0; k < 8; k++) {
      u16x8 vv = *(u16x8*)&SH2[mloc * 144 + nh + 8 * k];
      *(u16x8*)&dst[8 * k] = vv;
    }
  } else {
    // V: phase A writes transposed SH2[n][m] (packed 8B LDS writes)
#pragma unroll
    for (int i = 0; i < 4; i++) {
      const int mb = wm * 64 + i * 16 + quad * 4;
#pragma unroll
      for (int j = 0; j < 4; j++) {
        const int nn = wn * 64 + j * 16 + l15;
        u32x2 w;
        w[0] = pk2(acc[i][j][1], acc[i][j][0]);
        w[1] = pk2(acc[i][j][3], acc[i][j][2]);
        *(u32x2*)&SH2[nn * 144 + mb] = w;
      }
    }
    __syncthreads();
    // phase B: coalesced 16B stores to Vt[b,h,d,s]
    const int nloc = t >> 1, mh = (t & 1) * 64;
    const int ng = (n0 & 511) + nloc, h = ng >> 6, d = ng & 63;
    const int b = m0 >> 12, sb = (m0 & 4095) + mh;
    u16* dst = Vt + ((size_t)(b * NH + h) * HD + d) * SEQ + sb;
#pragma unroll
    for (int k = 0; k < 8; k++) {
      u16x8 vv = *(u16x8*)&SH2[nloc * 144 + mh + 8 * k];
      *(u16x8*)&dst[8 * k] = vv;
    }
  }
}

// ---------------------------------------------------------------------------
// Kernel 3: flash attention (non-causal, no-max softmax), K-SPLIT by 2.
// Block = 4 waves x 32 q, kr range = 2048 per split (16 chunks of 128).
// S^T = K @ Q^T (mfma_32x32x16, q on lanes).  P never touches LDS: the
// C-layout (kr=(reg&3)+8(reg>>2)+4hf) means each lane owns half of every
// PV B-frag; the other half lives in the same l31 lane of the other
// half-wave -> 2x shfl_xor(32) + cndmask assembly per 16-kr slice.
// Output: unnormalized bf16 O-partial [split][bh][q][d] + fp32 l-partial;
// combine_kernel normalizes (no-max softmax => partials are additive).
// ---------------------------------------------------------------------------
__global__ __launch_bounds__(256, 3) void attn_kernel(
    const u16* __restrict__ Q, const u16* __restrict__ K,
    const u16* __restrict__ Vt, u16* __restrict__ Opart,
    float* __restrict__ lpart)
{
  __shared__ u16 Kl[128][72];        // K chunk  [kr][d]
  __shared__ u16 Vl[64][136];        // V^T chunk [d][kr]
  const int qt = blockIdx.x, bh = blockIdx.y, spl = blockIdx.z;
  const int t = threadIdx.x, wave = t >> 6, lane = t & 63;
  const int l31 = lane & 31, hf = lane >> 5;
  const u16* Qb = Q + (size_t)bh * SEQ * HD;
  const u16* Kb = K + (size_t)bh * SEQ * HD;
  const u16* Vb = Vt + (size_t)bh * HD * SEQ;
  const int qw = qt * 128 + wave * 32;
  const int kbase = spl * 2048;

  bf16x8 bq[4];
#pragma unroll
  for (int kk = 0; kk < 4; kk++)
    bq[kk] = *(const bf16x8*)(Qb + (size_t)(qw + l31) * HD + kk * 16 + hf * 8);

  f32x16 oacc[2];
#pragma unroll
  for (int mt = 0; mt < 2; mt++)
#pragma unroll
    for (int r = 0; r < 16; r++) oacc[mt][r] = 0.0f;
  float lrun = 0.0f;

  for (int c = 0; c < 16; c++) {
    const int kc = kbase + c * 128;
    __syncthreads();
#pragma unroll
    for (int it = 0; it < 4; it++) {
      const int c4 = t + it * 256;
      {
        const int r = c4 >> 3, off = (c4 & 7) * 8;
        *(u16x8*)&Kl[r][off] =
            *(const u16x8*)(Kb + (size_t)(kc + r) * HD + off);
      }
      {
        const int d = c4 >> 4, off = (c4 & 15) * 8;
        *(u16x8*)&Vl[d][off] =
            *(const u16x8*)(Vb + (size_t)d * SEQ + kc + off);
      }
    }
    __syncthreads();

    // S^T = K @ Q^T  (128 x 32 per wave); Q pre-scaled by scale*log2e
    f32x16 sacc[4];
#pragma unroll
    for (int mt = 0; mt < 4; mt++)
#pragma unroll
      for (int r = 0; r < 16; r++) sacc[mt][r] = 0.0f;
#pragma unroll
    for (int kk = 0; kk < 4; kk++) {
#pragma unroll
      for (int mt = 0; mt < 4; mt++) {
        const bf16x8 ka =
            *(const bf16x8*)&Kl[mt * 32 + l31][kk * 16 + hf * 8];
        sacc[mt] = __builtin_amdgcn_mfma_f32_32x32x16_bf16(
            ka, bq[kk], sacc[mt], 0, 0, 0);
      }
    }

    // p = 2^s (no max), per-lane partial sum
    float ps = 0.0f;
#pragma unroll
    for (int mt = 0; mt < 4; mt++)
#pragma unroll
      for (int r = 0; r < 16; r++) {
        const float p = __builtin_amdgcn_exp2f(sacc[mt][r]);
        sacc[mt][r] = p;
        ps += p;
      }
    lrun += ps;

    // O^T += V^T @ P^T: B-frags assembled in-register via cross-half shfl
#pragma unroll
    for (int kk2 = 0; kk2 < 8; kk2++) {
      const int mt = kk2 >> 1, g = (kk2 & 1) * 8;
      const u32 a0 = pk2(sacc[mt][g + 1], sacc[mt][g + 0]);
      const u32 a1 = pk2(sacc[mt][g + 3], sacc[mt][g + 2]);
      const u32 b0 = pk2(sacc[mt][g + 5], sacc[mt][g + 4]);
      const u32 b1 = pk2(sacc[mt][g + 7], sacc[mt][g + 6]);
      const u32 s0 = hf ? a0 : b0;
      const u32 s1 = hf ? a1 : b1;
      const u32 r0 = __shfl_xor(s0, 32, 64);
      const u32 r1 = __shfl_xor(s1, 32, 64);
      u32x4 fr;
      fr[0] = hf ? r0 : a0;
      fr[1] = hf ? r1 : a1;
      fr[2] = hf ? b0 : r0;
      fr[3] = hf ? b1 : r1;
      const bf16x8 pb = __builtin_bit_cast(bf16x8, fr);
#pragma unroll
      for (int mt2 = 0; mt2 < 2; mt2++) {
        const bf16x8 va =
            *(const bf16x8*)&Vl[mt2 * 32 + l31][kk2 * 16 + hf * 8];
        oacc[mt2] = __builtin_amdgcn_mfma_f32_32x32x16_bf16(
            va, pb, oacc[mt2], 0, 0, 0);
      }
    }
  }

  // epilogue: unnormalized bf16 O-partial + l-partial
  const float lt = lrun + __shfl_xor(lrun, 32, 64);
  const int q = qw + l31;
  const size_t obase = ((size_t)(spl * 16 + bh) * SEQ + q) * HD;
#pragma unroll
  for (int mt2 = 0; mt2 < 2; mt2++)
#pragma unroll
    for (int gg = 0; gg < 4; gg++) {
      const int d0 = 32 * mt2 + 8 * gg + 4 * hf;
      u32x2 w;
      w[0] = pk2(oacc[mt2][4 * gg + 1], oacc[mt2][4 * gg + 0]);
      w[1] = pk2(oacc[mt2][4 * gg + 3], oacc[mt2][4 * gg + 2]);
      *(u32x2*)&Opart[obase + d0] = w;
    }
  if (hf == 0) lpart[(spl * 16 + bh) * SEQ + q] = lt;
}

// ---------------------------------------------------------------------------
// Kernel 3b: combine the two K-split partials, normalize, write Ob bf16.
// ---------------------------------------------------------------------------
__global__ __launch_bounds__(256) void combine_kernel(
    const u16* __restrict__ Opart, const float* __restrict__ lpart,
    u16* __restrict__ Ob)
{
  const int idx = blockIdx.x * 256 + threadIdx.x;
  const size_t o = (size_t)idx * 8;
  const int sg = idx >> 6;            // global row (b*4096+s)
  const int dcol = (idx & 63) * 8;
  const int b = sg >> 12, s = sg & 4095;
  const int h = dcol >> 6, d = dcol & 63;
  const int bh = b * NH + h;
  const size_t base = ((size_t)bh * SEQ + s) * HD + d;
  constexpr size_t SPLIT = (size_t)16 * SEQ * HD;
  const u16x8 p0 = *(const u16x8*)&Opart[base];
  const u16x8 p1 = *(const u16x8*)&Opart[SPLIT + base];
  const float l = lpart[bh * SEQ + s] + lpart[16 * SEQ + bh * SEQ + s];
  const float inv = __builtin_amdgcn_rcpf(l);
  float v[8];
#pragma unroll
  for (int k = 0; k < 8; k++) v[k] = (bf2f(p0[k]) + bf2f(p1[k])) * inv;
  u32x4 w = { pk2(v[1], v[0]), pk2(v[3], v[2]),
              pk2(v[5], v[4]), pk2(v[7], v[6]) };
  *(u32x4*)&Ob[o] = w;
}

// ---------------------------------------------------------------------------
extern "C" void kernel_launch(void* const* d_in, const int* in_sizes, int n_in,
                              void* d_out, int out_size, void* d_ws,
                              size_t ws_size, hipStream_t stream)
{
  const float* x     = (const float*)d_in[0];
  const float* gamma = (const float*)d_in[1];
  const float* beta  = (const float*)d_in[2];
  const float* wq    = (const float*)d_in[3];
  const float* wk    = (const float*)d_in[4];
  const float* wv    = (const float*)d_in[5];
  const float* wfc   = (const float*)d_in[6];
  float* out = (float*)d_out;

  char* ws = (char*)d_ws;
  u16*   Qb    = (u16*)(ws);                        //  8 MB [b,h,s,d] scaled
  u16*   Kb    = (u16*)(ws + ((size_t)8  << 20));   //  8 MB [b,h,s,d]
  u16*   Vt    = (u16*)(ws + ((size_t)16 << 20));   //  8 MB [b,h,d,s]
  u16*   Ob    = (u16*)(ws + ((size_t)24 << 20));   //  8 MB [b,s,h*64+d]
  u16*   Wb    = (u16*)(ws + ((size_t)32 << 20));   //  2 MB bf16 weights
  float* lpart = (float*)(ws + ((size_t)34 << 20)); //  0.5 MB
  u16*   Opart = (u16*)(ws + ((size_t)35 << 20));   // 16 MB [2][bh][q][d]
  u16*   xn    = (u16*)(ws + ((size_t)35 << 20));   //  8 MB, dead before attn
                                                    //  (aliases Opart safely)

  wconv_kernel<<<512, 256, 0, stream>>>(wq, wk, wv, wfc, Wb);
  ln_cast_kernel<<<2048, 256, 0, stream>>>(x, gamma, beta, xn);
  gemm_kernel<0><<<dim3(12, 64), 256, 0, stream>>>(xn, Wb, Qb, Kb, Vt, nullptr);
  attn_kernel<<<dim3(32, 16, 2), 256, 0, stream>>>(Qb, Kb, Vt, Opart, lpart);
  combine_kernel<<<2048, 256, 0, stream>>>(Opart, lpart, Ob);
  gemm_kernel<1><<<dim3(4, 64), 256, 0, stream>>>(
      Ob, Wb, nullptr, nullptr, nullptr, out);
}

// Round 5
// 231.743 us; speedup vs baseline: 1.0577x; 1.0577x over previous
//
#include <hip/hip_runtime.h>
#include <cstdint>
#include <cstddef>

typedef unsigned short u16;
typedef unsigned int   u32;
typedef __bf16 bf16x8 __attribute__((ext_vector_type(8)));
typedef float  f32x4  __attribute__((ext_vector_type(4)));
typedef float  f32x16 __attribute__((ext_vector_type(16)));
typedef u16    u16x8  __attribute__((ext_vector_type(8)));
typedef u16    u16x4  __attribute__((ext_vector_type(4)));
typedef u32    u32x2  __attribute__((ext_vector_type(2)));
typedef u32    u32x4  __attribute__((ext_vector_type(4)));

#define DI __device__ __forceinline__

constexpr int SEQ = 4096;
constexpr int DIM = 512;
constexpr int NH  = 8;
constexpr int HD  = 64;
// scale * log2(e): softmax in exp2 domain; folded into Q at GEMM-0 epilogue
constexpr float ATT_C1 = 0.125f * 1.44269504088896340736f;

DI u16 f2bf(float f) {   // round-half-up (<=1 ulp vs RNE)
  return (u16)((__builtin_bit_cast(u32, f) + 0x8000u) >> 16);
}

// pack two fp32 -> u32 of two bf16 (round-half-up): 2 adds + 1 v_perm
DI u32 pk2(float hi, float lo) {
  u32 uh = __builtin_bit_cast(u32, hi) + 0x8000u;
  u32 ul = __builtin_bit_cast(u32, lo) + 0x8000u;
  return __builtin_amdgcn_perm(uh, ul, 0x07060302u);
}

// ---------------------------------------------------------------------------
// Kernel 0: one-shot W fp32 -> bf16 (all four matrices into Wb[4][512][512])
// ---------------------------------------------------------------------------
__global__ __launch_bounds__(256) void wconv_kernel(
    const float* __restrict__ wq, const float* __restrict__ wk,
    const float* __restrict__ wv, const float* __restrict__ wfc,
    u16* __restrict__ Wb)
{
  const int idx  = blockIdx.x * 256 + threadIdx.x;
  const int base = idx * 8;
  const int mat  = base >> 18;
  const int off  = base & (512 * 512 - 1);
  const float* src = (mat == 0) ? wq : (mat == 1) ? wk : (mat == 2) ? wv : wfc;
  const float4 a = *(const float4*)(src + off);
  const float4 b = *(const float4*)(src + off + 4);
  u32x4 o = { pk2(a.y, a.x), pk2(a.w, a.z), pk2(b.y, b.x), pk2(b.w, b.z) };
  *(u32x4*)(Wb + base) = o;
}

// ---------------------------------------------------------------------------
// Kernel 1: LayerNorm (fp32) + cast to bf16.  One wave per row (64 lanes x 8).
// ---------------------------------------------------------------------------
__global__ __launch_bounds__(256) void ln_cast_kernel(
    const float* __restrict__ x, const float* __restrict__ gamma,
    const float* __restrict__ beta, u16* __restrict__ xn)
{
  const int row  = blockIdx.x * 4 + (threadIdx.x >> 6);
  const int lane = threadIdx.x & 63;
  const float* xr = x + (size_t)row * DIM + lane * 8;
  const float4 a = *(const float4*)xr;
  const float4 b = *(const float4*)(xr + 4);
  float s = a.x + a.y + a.z + a.w + b.x + b.y + b.z + b.w;
  float q = a.x*a.x + a.y*a.y + a.z*a.z + a.w*a.w
          + b.x*b.x + b.y*b.y + b.z*b.z + b.w*b.w;
#pragma unroll
  for (int m = 1; m < 64; m <<= 1) {
    s += __shfl_xor(s, m, 64);
    q += __shfl_xor(q, m, 64);
  }
  const float mu = s * (1.0f / DIM);
  const float rs = rsqrtf(q * (1.0f / DIM) - mu * mu + 1e-5f);
  const float4 g0 = *(const float4*)(gamma + lane * 8);
  const float4 g1 = *(const float4*)(gamma + lane * 8 + 4);
  const float4 e0 = *(const float4*)(beta + lane * 8);
  const float4 e1 = *(const float4*)(beta + lane * 8 + 4);
  const float v0 = (a.x - mu) * rs * g0.x + e0.x;
  const float v1 = (a.y - mu) * rs * g0.y + e0.y;
  const float v2 = (a.z - mu) * rs * g0.z + e0.z;
  const float v3 = (a.w - mu) * rs * g0.w + e0.w;
  const float v4 = (b.x - mu) * rs * g1.x + e1.x;
  const float v5 = (b.y - mu) * rs * g1.y + e1.y;
  const float v6 = (b.z - mu) * rs * g1.z + e1.z;
  const float v7 = (b.w - mu) * rs * g1.w + e1.w;
  u32x4 o = { pk2(v1, v0), pk2(v3, v2), pk2(v5, v4), pk2(v7, v6) };
  *(u32x4*)(xn + (size_t)row * DIM + lane * 8) = o;
}

// ---------------------------------------------------------------------------
// Kernel 2: 128x128x(BK=64) bf16 MFMA GEMM, C = A @ W^T (W pre-bf16).
//   N=1536 fused QKV; Q pre-scaled by ATT_C1.  Epilogue routes C through LDS
//   so global stores are coalesced 16B: Q,K -> [b,h,s,d], V -> Vt[b,h,d,s].
// ---------------------------------------------------------------------------
__global__ __launch_bounds__(256, 2) void gemm_qkv_kernel(
    const u16* __restrict__ A, const u16* __restrict__ Wb,
    u16* __restrict__ Qo, u16* __restrict__ Ko, u16* __restrict__ Vt)
{
  __shared__ u16 SH[2][128][72];
  const int m0 = blockIdx.y * 128, n0 = blockIdx.x * 128;
  const int t = threadIdx.x, wave = t >> 6, lane = t & 63;
  const int quad = lane >> 4, l15 = lane & 15;
  const int wm = wave >> 1, wn = wave & 1;
  const int mat = n0 >> 9;
  const u16* Wsrc = Wb + (size_t)mat * 512 * 512 + (size_t)(n0 & 511) * DIM;

  f32x4 acc[4][4];
#pragma unroll
  for (int i = 0; i < 4; i++)
#pragma unroll
    for (int j = 0; j < 4; j++)
#pragma unroll
      for (int r = 0; r < 4; r++) acc[i][j][r] = 0.0f;

  for (int kk = 0; kk < DIM; kk += 64) {
    __syncthreads();
#pragma unroll
    for (int it = 0; it < 4; it++) {
      const int c4 = t + it * 256;
      const int r = c4 >> 3, off = (c4 & 7) * 8;
      *(u16x8*)&SH[0][r][off] =
          *(const u16x8*)(A + (size_t)(m0 + r) * DIM + kk + off);
      *(u16x8*)&SH[1][r][off] =
          *(const u16x8*)(Wsrc + (size_t)r * DIM + kk + off);
    }
    __syncthreads();
#pragma unroll
    for (int kx = 0; kx < 2; kx++) {
      bf16x8 af[4], bfr[4];
#pragma unroll
      for (int i = 0; i < 4; i++)
        af[i] = *(const bf16x8*)&SH[0][wm * 64 + i * 16 + l15][kx * 32 + quad * 8];
#pragma unroll
      for (int j = 0; j < 4; j++)
        bfr[j] = *(const bf16x8*)&SH[1][wn * 64 + j * 16 + l15][kx * 32 + quad * 8];
#pragma unroll
      for (int i = 0; i < 4; i++)
#pragma unroll
        for (int j = 0; j < 4; j++)
          acc[i][j] = __builtin_amdgcn_mfma_f32_16x16x32_bf16(
              af[i], bfr[j], acc[i][j], 0, 0, 0);
    }
  }

  u16* SH2 = (u16*)SH;               // flat [128][144] view
  __syncthreads();
  if (mat < 2) {
    const float qs = (mat == 0) ? ATT_C1 : 1.0f;
#pragma unroll
    for (int i = 0; i < 4; i++) {
      const int mb = wm * 64 + i * 16 + quad * 4;
#pragma unroll
      for (int j = 0; j < 4; j++) {
        const int nn = wn * 64 + j * 16 + l15;
#pragma unroll
        for (int r = 0; r < 4; r++)
          SH2[(mb + r) * 144 + nn] = f2bf(acc[i][j][r] * qs);
      }
    }
    __syncthreads();
    const int mloc = t >> 1, nh = (t & 1) * 64;
    const int sg = m0 + mloc, b = sg >> 12, sl = sg & 4095;
    const int ng0 = (n0 & 511) + nh, h = ng0 >> 6;
    u16* dst = (mat == 0 ? Qo : Ko) +
               ((size_t)(b * NH + h) * SEQ + sl) * HD;
#pragma unroll
    for (int k = 0; k < 8; k++) {
      u16x8 vv = *(u16x8*)&SH2[mloc * 144 + nh + 8 * k];
      *(u16x8*)&dst[8 * k] = vv;
    }
  } else {
#pragma unroll
    for (int i = 0; i < 4; i++) {
      const int mb = wm * 64 + i * 16 + quad * 4;
#pragma unroll
      for (int j = 0; j < 4; j++) {
        const int nn = wn * 64 + j * 16 + l15;
        u32x2 w;
        w[0] = pk2(acc[i][j][1], acc[i][j][0]);
        w[1] = pk2(acc[i][j][3], acc[i][j][2]);
        *(u32x2*)&SH2[nn * 144 + mb] = w;
      }
    }
    __syncthreads();
    const int nloc = t >> 1, mh = (t & 1) * 64;
    const int ng = (n0 & 511) + nloc, h = ng >> 6, d = ng & 63;
    const int b = m0 >> 12, sb = (m0 & 4095) + mh;
    u16* dst = Vt + ((size_t)(b * NH + h) * HD + d) * SEQ + sb;
#pragma unroll
    for (int k = 0; k < 8; k++) {
      u16x8 vv = *(u16x8*)&SH2[nloc * 144 + mh + 8 * k];
      *(u16x8*)&dst[8 * k] = vv;
    }
  }
}

// ---------------------------------------------------------------------------
// Kernel 3: flash attention (non-causal, no-max softmax).
// Block = 4 waves over 64 q-rows: wave = (qgrp in {0,1}) x (kr-half in {0,1}).
// Each wave: 32 q x 64 kr per 128-kr chunk -> sacc is only 2 x f32x16, so
// total regs (VGPR+acc) fit 128 -> 4 waves/SIMD; grid 1024 = 4 blocks/CU
// -> 16 waves/CU (vs 8 before; R3/R4 were register-capped at 2 waves/SIMD
// because sacc[4]+oacc[2] accumulators pushed unified-file use to ~180).
// kr-halves combine via one LDS round trip in the epilogue (no global
// partials, no combine kernel).  S^T = K @ Q^T (mfma_32x32x16, q on lanes);
// P assembled in-register via cross-half shfl (verified R4).  LDS is
// unpadded + XOR-swizzled (col ^ ((row&7)*8)) -> aligned b128, no conflicts.
// bh from XCD swizzle so each bh's K/V (2MB) stays in one XCD's L2.
// ---------------------------------------------------------------------------
__global__ __launch_bounds__(256, 4) void attn_kernel(
    const u16* __restrict__ Q, const u16* __restrict__ K,
    const u16* __restrict__ Vt, u16* __restrict__ O)
{
  __shared__ u16 Kl[128][64];   // [kr][d],  col ^= (kr&7)*8
  __shared__ u16 Vl[64][128];   // [d][kr],  col ^= (d&7)*8
  const int bid = blockIdx.x;
  const int qt = bid >> 4;
  const int bh = (bid & 7) * 2 + ((bid >> 3) & 1);   // XCD-locality swizzle
  const int b = bh >> 3, h = bh & 7;
  const int t = threadIdx.x, wave = t >> 6, lane = t & 63;
  const int l31 = lane & 31, hf = lane >> 5;
  const int qgrp = wave & 1, krh = wave >> 1;
  const u16* Qb = Q + (size_t)bh * SEQ * HD;
  const u16* Kb = K + (size_t)bh * SEQ * HD;
  const u16* Vb = Vt + (size_t)bh * HD * SEQ;
  const int qw = qt * 64 + qgrp * 32;

  bf16x8 bq[4];
#pragma unroll
  for (int kk = 0; kk < 4; kk++)
    bq[kk] = *(const bf16x8*)(Qb + (size_t)(qw + l31) * HD + kk * 16 + hf * 8);

  f32x16 oacc[2];
#pragma unroll
  for (int mt = 0; mt < 2; mt++)
#pragma unroll
    for (int r = 0; r < 16; r++) oacc[mt][r] = 0.0f;
  float lrun = 0.0f;

  for (int kc = 0; kc < SEQ; kc += 128) {
    __syncthreads();
#pragma unroll
    for (int it = 0; it < 4; it++) {
      const int c4 = t + it * 256;
      {
        const int r = c4 >> 3, off = (c4 & 7) * 8;
        *(u16x8*)&Kl[r][off ^ ((r & 7) * 8)] =
            *(const u16x8*)(Kb + (size_t)(kc + r) * HD + off);
      }
      {
        const int d = c4 >> 4, off = (c4 & 15) * 8;
        *(u16x8*)&Vl[d][off ^ ((d & 7) * 8)] =
            *(const u16x8*)(Vb + (size_t)d * SEQ + kc + off);
      }
    }
    __syncthreads();

    // S^T = K @ Q^T: this wave's 64-kr half x 32 q
    f32x16 sacc[2];
#pragma unroll
    for (int mt = 0; mt < 2; mt++)
#pragma unroll
      for (int r = 0; r < 16; r++) sacc[mt][r] = 0.0f;
#pragma unroll
    for (int kk = 0; kk < 4; kk++) {
#pragma unroll
      for (int mt = 0; mt < 2; mt++) {
        const int row = krh * 64 + mt * 32 + l31;
        const bf16x8 ka = *(const bf16x8*)
            &Kl[row][(kk * 16 + hf * 8) ^ ((row & 7) * 8)];
        sacc[mt] = __builtin_amdgcn_mfma_f32_32x32x16_bf16(
            ka, bq[kk], sacc[mt], 0, 0, 0);
      }
    }

    // p = 2^s (no max; Q pre-scaled), per-lane partial sum
    float ps = 0.0f;
#pragma unroll
    for (int mt = 0; mt < 2; mt++)
#pragma unroll
      for (int r = 0; r < 16; r++) {
        const float p = __builtin_amdgcn_exp2f(sacc[mt][r]);
        sacc[mt][r] = p;
        ps += p;
      }
    lrun += ps;

    // O^T += V^T @ P^T over this kr-half; P B-frags via cross-half shfl
#pragma unroll
    for (int kk2 = 0; kk2 < 4; kk2++) {
      const int mt = kk2 >> 1, g = (kk2 & 1) * 8;
      const u32 a0 = pk2(sacc[mt][g + 1], sacc[mt][g + 0]);
      const u32 a1 = pk2(sacc[mt][g + 3], sacc[mt][g + 2]);
      const u32 b0 = pk2(sacc[mt][g + 5], sacc[mt][g + 4]);
      const u32 b1 = pk2(sacc[mt][g + 7], sacc[mt][g + 6]);
      const u32 s0 = hf ? a0 : b0;
      const u32 s1 = hf ? a1 : b1;
      const u32 r0 = __shfl_xor(s0, 32, 64);
      const u32 r1 = __shfl_xor(s1, 32, 64);
      u32x4 fr;
      fr[0] = hf ? r0 : a0;
      fr[1] = hf ? r1 : a1;
      fr[2] = hf ? b0 : r0;
      fr[3] = hf ? b1 : r1;
      const bf16x8 pb = __builtin_bit_cast(bf16x8, fr);
#pragma unroll
      for (int mt2 = 0; mt2 < 2; mt2++) {
        const int row = mt2 * 32 + l31;
        const bf16x8 va = *(const bf16x8*)
            &Vl[row][(krh * 64 + kk2 * 16 + hf * 8) ^ ((row & 7) * 8)];
        oacc[mt2] = __builtin_amdgcn_mfma_f32_32x32x16_bf16(
            va, pb, oacc[mt2], 0, 0, 0);
      }
    }
  }

  // cross-(kr-half) combine via LDS, then normalize + store
  float lt = lrun + __shfl_xor(lrun, 32, 64);
  __syncthreads();
  float* Ofs = (float*)&Kl[0][0];        // 2*32*68*4 = 17408 B (< 32KB LDS)
  float* Lfs = Ofs + 2 * 32 * 68;
  if (krh == 1) {
#pragma unroll
    for (int mt2 = 0; mt2 < 2; mt2++)
#pragma unroll
      for (int gg = 0; gg < 4; gg++) {
        f32x4 v = { oacc[mt2][4 * gg + 0], oacc[mt2][4 * gg + 1],
                    oacc[mt2][4 * gg + 2], oacc[mt2][4 * gg + 3] };
        *(f32x4*)&Ofs[(qgrp * 32 + l31) * 68 + 32 * mt2 + 8 * gg + 4 * hf] = v;
      }
    if (hf == 0) Lfs[qgrp * 32 + l31] = lt;
  }
  __syncthreads();
  if (krh == 0) {
    lt += Lfs[qgrp * 32 + l31];
    const float inv = 1.0f / lt;
    const int s = qw + l31;
    u16* Ob = O + ((size_t)(b * SEQ + s)) * DIM + h * HD;
#pragma unroll
    for (int mt2 = 0; mt2 < 2; mt2++)
#pragma unroll
      for (int gg = 0; gg < 4; gg++) {
        const f32x4 v = *(const f32x4*)
            &Ofs[(qgrp * 32 + l31) * 68 + 32 * mt2 + 8 * gg + 4 * hf];
        u32x2 w;
        w[0] = pk2((oacc[mt2][4 * gg + 1] + v[1]) * inv,
                   (oacc[mt2][4 * gg + 0] + v[0]) * inv);
        w[1] = pk2((oacc[mt2][4 * gg + 3] + v[3]) * inv,
                   (oacc[mt2][4 * gg + 2] + v[2]) * inv);
        *(u32x2*)&Ob[32 * mt2 + 8 * gg + 4 * hf] = w;
      }
  }
}

// ---------------------------------------------------------------------------
// Kernel 4: output GEMM 64x64 tiles (grid 8x128 = 1024 blocks for occupancy).
// ---------------------------------------------------------------------------
__global__ __launch_bounds__(256, 2) void gemm_fc_kernel(
    const u16* __restrict__ A, const u16* __restrict__ Wb,
    float* __restrict__ Co)
{
  __shared__ u16 As[64][72];
  __shared__ u16 Bs[64][72];
  const int m0 = blockIdx.y * 64, n0 = blockIdx.x * 64;
  const int t = threadIdx.x, wave = t >> 6, lane = t & 63;
  const int quad = lane >> 4, l15 = lane & 15;
  const int wm = wave >> 1, wn = wave & 1;
  const u16* Wsrc = Wb + (size_t)3 * 512 * 512 + (size_t)n0 * DIM;

  f32x4 acc[2][2];
#pragma unroll
  for (int i = 0; i < 2; i++)
#pragma unroll
    for (int j = 0; j < 2; j++)
#pragma unroll
      for (int r = 0; r < 4; r++) acc[i][j][r] = 0.0f;

  for (int kk = 0; kk < DIM; kk += 64) {
    __syncthreads();
#pragma unroll
    for (int it = 0; it < 2; it++) {
      const int c4 = t + it * 256;
      const int r = c4 >> 3, off = (c4 & 7) * 8;
      *(u16x8*)&As[r][off] =
          *(const u16x8*)(A + (size_t)(m0 + r) * DIM + kk + off);
      *(u16x8*)&Bs[r][off] =
          *(const u16x8*)(Wsrc + (size_t)r * DIM + kk + off);
    }
    __syncthreads();
#pragma unroll
    for (int kx = 0; kx < 2; kx++) {
      bf16x8 af[2], bfr[2];
#pragma unroll
      for (int i = 0; i < 2; i++)
        af[i] = *(const bf16x8*)&As[wm * 32 + i * 16 + l15][kx * 32 + quad * 8];
#pragma unroll
      for (int j = 0; j < 2; j++)
        bfr[j] = *(const bf16x8*)&Bs[wn * 32 + j * 16 + l15][kx * 32 + quad * 8];
#pragma unroll
      for (int i = 0; i < 2; i++)
#pragma unroll
        for (int j = 0; j < 2; j++)
          acc[i][j] = __builtin_amdgcn_mfma_f32_16x16x32_bf16(
              af[i], bfr[j], acc[i][j], 0, 0, 0);
    }
  }

#pragma unroll
  for (int i = 0; i < 2; i++) {
    const int m = m0 + wm * 32 + i * 16 + quad * 4;
#pragma unroll
    for (int j = 0; j < 2; j++) {
      const int n = n0 + wn * 32 + j * 16 + l15;
#pragma unroll
      for (int r = 0; r < 4; r++)
        Co[(size_t)(m + r) * DIM + n] = acc[i][j][r];
    }
  }
}

// ---------------------------------------------------------------------------
extern "C" void kernel_launch(void* const* d_in, const int* in_sizes, int n_in,
                              void* d_out, int out_size, void* d_ws,
                              size_t ws_size, hipStream_t stream)
{
  const float* x     = (const float*)d_in[0];
  const float* gamma = (const float*)d_in[1];
  const float* beta  = (const float*)d_in[2];
  const float* wq    = (const float*)d_in[3];
  const float* wk    = (const float*)d_in[4];
  const float* wv    = (const float*)d_in[5];
  const float* wfc   = (const float*)d_in[6];
  float* out = (float*)d_out;

  char* ws = (char*)d_ws;
  u16* Qb = (u16*)(ws);                       //  8 MB [b,h,s,d] (pre-scaled)
  u16* Kb = (u16*)(ws + ((size_t)8  << 20));  //  8 MB [b,h,s,d]
  u16* Vt = (u16*)(ws + ((size_t)16 << 20));  //  8 MB [b,h,d,s]
  u16* Ob = (u16*)(ws + ((size_t)24 << 20));  //  8 MB [b,s,h*64+d]
  u16* Wb = (u16*)(ws + ((size_t)32 << 20));  //  2 MB bf16 weights
  u16* xn = (u16*)(ws + ((size_t)34 << 20));  //  8 MB [8192][512] bf16

  wconv_kernel<<<512, 256, 0, stream>>>(wq, wk, wv, wfc, Wb);
  ln_cast_kernel<<<2048, 256, 0, stream>>>(x, gamma, beta, xn);
  gemm_qkv_kernel<<<dim3(12, 64), 256, 0, stream>>>(xn, Wb, Qb, Kb, Vt);
  attn_kernel<<<1024, 256, 0, stream>>>(Qb, Kb, Vt, Ob);
  gemm_fc_kernel<<<dim3(8, 128), 256, 0, stream>>>(Ob, Wb, out);
}

// Round 6
// 218.556 us; speedup vs baseline: 1.1215x; 1.0603x over previous
//
#include <hip/hip_runtime.h>
#include <cstdint>
#include <cstddef>

typedef unsigned short u16;
typedef unsigned int   u32;
typedef __bf16 bf16x8 __attribute__((ext_vector_type(8)));
typedef float  f32x4  __attribute__((ext_vector_type(4)));
typedef float  f32x16 __attribute__((ext_vector_type(16)));
typedef u16    u16x8  __attribute__((ext_vector_type(8)));
typedef u16    u16x4  __attribute__((ext_vector_type(4)));
typedef u32    u32x2  __attribute__((ext_vector_type(2)));
typedef u32    u32x4  __attribute__((ext_vector_type(4)));

#define DI __device__ __forceinline__

constexpr int SEQ = 4096;
constexpr int DIM = 512;
constexpr int NH  = 8;
constexpr int HD  = 64;
// scale * log2(e): softmax in exp2 domain; folded into Q at GEMM-0 epilogue
constexpr float ATT_C1 = 0.125f * 1.44269504088896340736f;

DI u16 f2bf(float f) {   // round-half-up (<=1 ulp vs RNE)
  return (u16)((__builtin_bit_cast(u32, f) + 0x8000u) >> 16);
}

// pack two fp32 -> u32 of two bf16 (round-half-up): 2 adds + 1 v_perm
DI u32 pk2(float hi, float lo) {
  u32 uh = __builtin_bit_cast(u32, hi) + 0x8000u;
  u32 ul = __builtin_bit_cast(u32, lo) + 0x8000u;
  return __builtin_amdgcn_perm(uh, ul, 0x07060302u);
}

// ---------------------------------------------------------------------------
// Kernel 1: prep = wconv (blocks 0..511) + LayerNorm+cast (blocks 512..2559).
// Merged to save a launch; branch is block-uniform.
// ---------------------------------------------------------------------------
__global__ __launch_bounds__(256) void prep_kernel(
    const float* __restrict__ x, const float* __restrict__ gamma,
    const float* __restrict__ beta,
    const float* __restrict__ wq, const float* __restrict__ wk,
    const float* __restrict__ wv, const float* __restrict__ wfc,
    u16* __restrict__ Wb, u16* __restrict__ xn)
{
  if (blockIdx.x < 512) {
    const int idx  = blockIdx.x * 256 + threadIdx.x;
    const int base = idx * 8;
    const int mat  = base >> 18;
    const int off  = base & (512 * 512 - 1);
    const float* src = (mat == 0) ? wq : (mat == 1) ? wk : (mat == 2) ? wv : wfc;
    const float4 a = *(const float4*)(src + off);
    const float4 b = *(const float4*)(src + off + 4);
    u32x4 o = { pk2(a.y, a.x), pk2(a.w, a.z), pk2(b.y, b.x), pk2(b.w, b.z) };
    *(u32x4*)(Wb + base) = o;
    return;
  }
  const int row  = (blockIdx.x - 512) * 4 + (threadIdx.x >> 6);
  const int lane = threadIdx.x & 63;
  const float* xr = x + (size_t)row * DIM + lane * 8;
  const float4 a = *(const float4*)xr;
  const float4 b = *(const float4*)(xr + 4);
  float s = a.x + a.y + a.z + a.w + b.x + b.y + b.z + b.w;
  float q = a.x*a.x + a.y*a.y + a.z*a.z + a.w*a.w
          + b.x*b.x + b.y*b.y + b.z*b.z + b.w*b.w;
#pragma unroll
  for (int m = 1; m < 64; m <<= 1) {
    s += __shfl_xor(s, m, 64);
    q += __shfl_xor(q, m, 64);
  }
  const float mu = s * (1.0f / DIM);
  const float rs = rsqrtf(q * (1.0f / DIM) - mu * mu + 1e-5f);
  const float4 g0 = *(const float4*)(gamma + lane * 8);
  const float4 g1 = *(const float4*)(gamma + lane * 8 + 4);
  const float4 e0 = *(const float4*)(beta + lane * 8);
  const float4 e1 = *(const float4*)(beta + lane * 8 + 4);
  const float v0 = (a.x - mu) * rs * g0.x + e0.x;
  const float v1 = (a.y - mu) * rs * g0.y + e0.y;
  const float v2 = (a.z - mu) * rs * g0.z + e0.z;
  const float v3 = (a.w - mu) * rs * g0.w + e0.w;
  const float v4 = (b.x - mu) * rs * g1.x + e1.x;
  const float v5 = (b.y - mu) * rs * g1.y + e1.y;
  const float v6 = (b.z - mu) * rs * g1.z + e1.z;
  const float v7 = (b.w - mu) * rs * g1.w + e1.w;
  u32x4 o = { pk2(v1, v0), pk2(v3, v2), pk2(v5, v4), pk2(v7, v6) };
  *(u32x4*)(xn + (size_t)row * DIM + lane * 8) = o;
}

// ---------------------------------------------------------------------------
// Kernel 2: 128x128x(BK=64) bf16 MFMA GEMM, C = A @ W^T (W pre-bf16),
// REGISTER-PREFETCHED staging: chunk k+1's global loads are issued before
// chunk k's compute, so the pre-barrier vmcnt wait lands one chunk later
// (removes ~400cyc naked L2 latency per k-iter -- the R4/R5 barrier drain).
//   N=1536 fused QKV; Q pre-scaled by ATT_C1.  Epilogue routes C through LDS
//   so global stores are coalesced 16B: Q,K -> [b,h,s,d], V -> Vt[b,h,d,s].
// ---------------------------------------------------------------------------
__global__ __launch_bounds__(256, 3) void gemm_qkv_kernel(
    const u16* __restrict__ A, const u16* __restrict__ Wb,
    u16* __restrict__ Qo, u16* __restrict__ Ko, u16* __restrict__ Vt)
{
  __shared__ u16 SH[2][128][72];
  const int m0 = blockIdx.y * 128, n0 = blockIdx.x * 128;
  const int t = threadIdx.x, wave = t >> 6, lane = t & 63;
  const int quad = lane >> 4, l15 = lane & 15;
  const int wm = wave >> 1, wn = wave & 1;
  const int mat = n0 >> 9;
  const u16* Wsrc = Wb + (size_t)mat * 512 * 512 + (size_t)(n0 & 511) * DIM;

  f32x4 acc[4][4];
#pragma unroll
  for (int i = 0; i < 4; i++)
#pragma unroll
    for (int j = 0; j < 4; j++)
#pragma unroll
      for (int r = 0; r < 4; r++) acc[i][j][r] = 0.0f;

  u16x8 pfA[4], pfB[4];
#pragma unroll
  for (int it = 0; it < 4; it++) {
    const int c4 = t + it * 256;
    const int r = c4 >> 3, off = (c4 & 7) * 8;
    pfA[it] = *(const u16x8*)(A + (size_t)(m0 + r) * DIM + off);
    pfB[it] = *(const u16x8*)(Wsrc + (size_t)r * DIM + off);
  }

  for (int kk = 0; kk < DIM; kk += 64) {
    __syncthreads();
#pragma unroll
    for (int it = 0; it < 4; it++) {
      const int c4 = t + it * 256;
      const int r = c4 >> 3, off = (c4 & 7) * 8;
      *(u16x8*)&SH[0][r][off] = pfA[it];
      *(u16x8*)&SH[1][r][off] = pfB[it];
    }
    if (kk + 64 < DIM) {
#pragma unroll
      for (int it = 0; it < 4; it++) {
        const int c4 = t + it * 256;
        const int r = c4 >> 3, off = (c4 & 7) * 8;
        pfA[it] = *(const u16x8*)(A + (size_t)(m0 + r) * DIM + kk + 64 + off);
        pfB[it] = *(const u16x8*)(Wsrc + (size_t)r * DIM + kk + 64 + off);
      }
    }
    __syncthreads();
#pragma unroll
    for (int kx = 0; kx < 2; kx++) {
      bf16x8 af[4], bfr[4];
#pragma unroll
      for (int i = 0; i < 4; i++)
        af[i] = *(const bf16x8*)&SH[0][wm * 64 + i * 16 + l15][kx * 32 + quad * 8];
#pragma unroll
      for (int j = 0; j < 4; j++)
        bfr[j] = *(const bf16x8*)&SH[1][wn * 64 + j * 16 + l15][kx * 32 + quad * 8];
#pragma unroll
      for (int i = 0; i < 4; i++)
#pragma unroll
        for (int j = 0; j < 4; j++)
          acc[i][j] = __builtin_amdgcn_mfma_f32_16x16x32_bf16(
              af[i], bfr[j], acc[i][j], 0, 0, 0);
    }
  }

  u16* SH2 = (u16*)SH;               // flat [128][144] view
  __syncthreads();
  if (mat < 2) {
    const float qs = (mat == 0) ? ATT_C1 : 1.0f;
#pragma unroll
    for (int i = 0; i < 4; i++) {
      const int mb = wm * 64 + i * 16 + quad * 4;
#pragma unroll
      for (int j = 0; j < 4; j++) {
        const int nn = wn * 64 + j * 16 + l15;
#pragma unroll
        for (int r = 0; r < 4; r++)
          SH2[(mb + r) * 144 + nn] = f2bf(acc[i][j][r] * qs);
      }
    }
    __syncthreads();
    const int mloc = t >> 1, nh = (t & 1) * 64;
    const int sg = m0 + mloc, b = sg >> 12, sl = sg & 4095;
    const int ng0 = (n0 & 511) + nh, h = ng0 >> 6;
    u16* dst = (mat == 0 ? Qo : Ko) +
               ((size_t)(b * NH + h) * SEQ + sl) * HD;
#pragma unroll
    for (int k = 0; k < 8; k++) {
      u16x8 vv = *(u16x8*)&SH2[mloc * 144 + nh + 8 * k];
      *(u16x8*)&dst[8 * k] = vv;
    }
  } else {
#pragma unroll
    for (int i = 0; i < 4; i++) {
      const int mb = wm * 64 + i * 16 + quad * 4;
#pragma unroll
      for (int j = 0; j < 4; j++) {
        const int nn = wn * 64 + j * 16 + l15;
        u32x2 w;
        w[0] = pk2(acc[i][j][1], acc[i][j][0]);
        w[1] = pk2(acc[i][j][3], acc[i][j][2]);
        *(u32x2*)&SH2[nn * 144 + mb] = w;
      }
    }
    __syncthreads();
    const int nloc = t >> 1, mh = (t & 1) * 64;
    const int ng = (n0 & 511) + nloc, h = ng >> 6, d = ng & 63;
    const int b = m0 >> 12, sb = (m0 & 4095) + mh;
    u16* dst = Vt + ((size_t)(b * NH + h) * HD + d) * SEQ + sb;
#pragma unroll
    for (int k = 0; k < 8; k++) {
      u16x8 vv = *(u16x8*)&SH2[nloc * 144 + mh + 8 * k];
      *(u16x8*)&dst[8 * k] = vv;
    }
  }
}

// ---------------------------------------------------------------------------
// Kernel 3: flash attention (non-causal, no-max softmax), R5 tiling
// (4 waves = 2 qgrp x 2 krh over 64q x 128kr chunks) + REGISTER PREFETCH:
// chunk c+1's K/V global loads issue before chunk c's compute, so the
// vmcnt drain that R4/R5 paid at every barrier is off the critical path.
// The 2nd barrier now only waits for ds_writes.  Costs 32 VGPRs ->
// launch_bounds(256,3) (12 waves/CU; R4 vs R5 showed >=8 is sufficient).
// S^T = K @ Q^T (mfma_32x32x16, q on lanes); P B-frags assembled in-register
// via cross-half shfl; LDS XOR-swizzled (col ^ ((row&7)*8)), conflict-free.
// bh from XCD swizzle so each bh's K/V (2MB) stays in one XCD's L2.
// ---------------------------------------------------------------------------
__global__ __launch_bounds__(256, 3) void attn_kernel(
    const u16* __restrict__ Q, const u16* __restrict__ K,
    const u16* __restrict__ Vt, u16* __restrict__ O)
{
  __shared__ u16 Kl[128][64];   // [kr][d],  col ^= (kr&7)*8
  __shared__ u16 Vl[64][128];   // [d][kr],  col ^= (d&7)*8
  const int bid = blockIdx.x;
  const int qt = bid >> 4;
  const int bh = (bid & 7) * 2 + ((bid >> 3) & 1);   // XCD-locality swizzle
  const int b = bh >> 3, h = bh & 7;
  const int t = threadIdx.x, wave = t >> 6, lane = t & 63;
  const int l31 = lane & 31, hf = lane >> 5;
  const int qgrp = wave & 1, krh = wave >> 1;
  const u16* Qb = Q + (size_t)bh * SEQ * HD;
  const u16* Kb = K + (size_t)bh * SEQ * HD;
  const u16* Vb = Vt + (size_t)bh * HD * SEQ;
  const int qw = qt * 64 + qgrp * 32;

  bf16x8 bq[4];
#pragma unroll
  for (int kk = 0; kk < 4; kk++)
    bq[kk] = *(const bf16x8*)(Qb + (size_t)(qw + l31) * HD + kk * 16 + hf * 8);

  f32x16 oacc[2];
#pragma unroll
  for (int mt = 0; mt < 2; mt++)
#pragma unroll
    for (int r = 0; r < 16; r++) oacc[mt][r] = 0.0f;
  float lrun = 0.0f;

  // prefetch chunk 0 into registers
  u16x8 pfK[4], pfV[4];
#pragma unroll
  for (int it = 0; it < 4; it++) {
    const int c4 = t + it * 256;
    const int rK = c4 >> 3, offK = (c4 & 7) * 8;
    pfK[it] = *(const u16x8*)(Kb + (size_t)rK * HD + offK);
    const int dV = c4 >> 4, offV = (c4 & 15) * 8;
    pfV[it] = *(const u16x8*)(Vb + (size_t)dV * SEQ + offV);
  }

  for (int kc = 0; kc < SEQ; kc += 128) {
    __syncthreads();             // previous chunk's LDS reads complete
#pragma unroll
    for (int it = 0; it < 4; it++) {
      const int c4 = t + it * 256;
      const int rK = c4 >> 3, offK = (c4 & 7) * 8;
      *(u16x8*)&Kl[rK][offK ^ ((rK & 7) * 8)] = pfK[it];
      const int dV = c4 >> 4, offV = (c4 & 15) * 8;
      *(u16x8*)&Vl[dV][offV ^ ((dV & 7) * 8)] = pfV[it];
    }
    if (kc + 128 < SEQ) {        // issue next chunk's loads NOW
#pragma unroll
      for (int it = 0; it < 4; it++) {
        const int c4 = t + it * 256;
        const int rK = c4 >> 3, offK = (c4 & 7) * 8;
        pfK[it] = *(const u16x8*)(Kb + (size_t)(kc + 128 + rK) * HD + offK);
        const int dV = c4 >> 4, offV = (c4 & 15) * 8;
        pfV[it] = *(const u16x8*)(Vb + (size_t)dV * SEQ + kc + 128 + offV);
      }
    }
    __syncthreads();             // ds_writes visible (no vmcnt drain here)

    // S^T = K @ Q^T: this wave's 64-kr half x 32 q
    f32x16 sacc[2];
#pragma unroll
    for (int mt = 0; mt < 2; mt++)
#pragma unroll
      for (int r = 0; r < 16; r++) sacc[mt][r] = 0.0f;
#pragma unroll
    for (int kk = 0; kk < 4; kk++) {
#pragma unroll
      for (int mt = 0; mt < 2; mt++) {
        const int row = krh * 64 + mt * 32 + l31;
        const bf16x8 ka = *(const bf16x8*)
            &Kl[row][(kk * 16 + hf * 8) ^ ((row & 7) * 8)];
        sacc[mt] = __builtin_amdgcn_mfma_f32_32x32x16_bf16(
            ka, bq[kk], sacc[mt], 0, 0, 0);
      }
    }

    // p = 2^s (no max; Q pre-scaled), per-lane partial sum
    float ps = 0.0f;
#pragma unroll
    for (int mt = 0; mt < 2; mt++)
#pragma unroll
      for (int r = 0; r < 16; r++) {
        const float p = __builtin_amdgcn_exp2f(sacc[mt][r]);
        sacc[mt][r] = p;
        ps += p;
      }
    lrun += ps;

    // O^T += V^T @ P^T over this kr-half; P B-frags via cross-half shfl
#pragma unroll
    for (int kk2 = 0; kk2 < 4; kk2++) {
      const int mt = kk2 >> 1, g = (kk2 & 1) * 8;
      const u32 a0 = pk2(sacc[mt][g + 1], sacc[mt][g + 0]);
      const u32 a1 = pk2(sacc[mt][g + 3], sacc[mt][g + 2]);
      const u32 b0 = pk2(sacc[mt][g + 5], sacc[mt][g + 4]);
      const u32 b1 = pk2(sacc[mt][g + 7], sacc[mt][g + 6]);
      const u32 s0 = hf ? a0 : b0;
      const u32 s1 = hf ? a1 : b1;
      const u32 r0 = __shfl_xor(s0, 32, 64);
      const u32 r1 = __shfl_xor(s1, 32, 64);
      u32x4 fr;
      fr[0] = hf ? r0 : a0;
      fr[1] = hf ? r1 : a1;
      fr[2] = hf ? b0 : r0;
      fr[3] = hf ? b1 : r1;
      const bf16x8 pb = __builtin_bit_cast(bf16x8, fr);
#pragma unroll
      for (int mt2 = 0; mt2 < 2; mt2++) {
        const int row = mt2 * 32 + l31;
        const bf16x8 va = *(const bf16x8*)
            &Vl[row][(krh * 64 + kk2 * 16 + hf * 8) ^ ((row & 7) * 8)];
        oacc[mt2] = __builtin_amdgcn_mfma_f32_32x32x16_bf16(
            va, pb, oacc[mt2], 0, 0, 0);
      }
    }
  }

  // cross-(kr-half) combine via LDS, then normalize + store
  float lt = lrun + __shfl_xor(lrun, 32, 64);
  __syncthreads();
  float* Ofs = (float*)&Kl[0][0];        // 2*32*68*4 = 17408 B
  float* Lfs = Ofs + 2 * 32 * 68;
  if (krh == 1) {
#pragma unroll
    for (int mt2 = 0; mt2 < 2; mt2++)
#pragma unroll
      for (int gg = 0; gg < 4; gg++) {
        f32x4 v = { oacc[mt2][4 * gg + 0], oacc[mt2][4 * gg + 1],
                    oacc[mt2][4 * gg + 2], oacc[mt2][4 * gg + 3] };
        *(f32x4*)&Ofs[(qgrp * 32 + l31) * 68 + 32 * mt2 + 8 * gg + 4 * hf] = v;
      }
    if (hf == 0) Lfs[qgrp * 32 + l31] = lt;
  }
  __syncthreads();
  if (krh == 0) {
    lt += Lfs[qgrp * 32 + l31];
    const float inv = 1.0f / lt;
    const int s = qw + l31;
    u16* Ob = O + ((size_t)(b * SEQ + s)) * DIM + h * HD;
#pragma unroll
    for (int mt2 = 0; mt2 < 2; mt2++)
#pragma unroll
      for (int gg = 0; gg < 4; gg++) {
        const f32x4 v = *(const f32x4*)
            &Ofs[(qgrp * 32 + l31) * 68 + 32 * mt2 + 8 * gg + 4 * hf];
        u32x2 w;
        w[0] = pk2((oacc[mt2][4 * gg + 1] + v[1]) * inv,
                   (oacc[mt2][4 * gg + 0] + v[0]) * inv);
        w[1] = pk2((oacc[mt2][4 * gg + 3] + v[3]) * inv,
                   (oacc[mt2][4 * gg + 2] + v[2]) * inv);
        *(u32x2*)&Ob[32 * mt2 + 8 * gg + 4 * hf] = w;
      }
  }
}

// ---------------------------------------------------------------------------
// Kernel 4: output GEMM 64x64 tiles, register-prefetched staging.
// ---------------------------------------------------------------------------
__global__ __launch_bounds__(256, 3) void gemm_fc_kernel(
    const u16* __restrict__ A, const u16* __restrict__ Wb,
    float* __restrict__ Co)
{
  __shared__ u16 As[64][72];
  __shared__ u16 Bs[64][72];
  const int m0 = blockIdx.y * 64, n0 = blockIdx.x * 64;
  const int t = threadIdx.x, wave = t >> 6, lane = t & 63;
  const int quad = lane >> 4, l15 = lane & 15;
  const int wm = wave >> 1, wn = wave & 1;
  const u16* Wsrc = Wb + (size_t)3 * 512 * 512 + (size_t)n0 * DIM;

  f32x4 acc[2][2];
#pragma unroll
  for (int i = 0; i < 2; i++)
#pragma unroll
    for (int j = 0; j < 2; j++)
#pragma unroll
      for (int r = 0; r < 4; r++) acc[i][j][r] = 0.0f;

  u16x8 pfA[2], pfB[2];
#pragma unroll
  for (int it = 0; it < 2; it++) {
    const int c4 = t + it * 256;
    const int r = c4 >> 3, off = (c4 & 7) * 8;
    pfA[it] = *(const u16x8*)(A + (size_t)(m0 + r) * DIM + off);
    pfB[it] = *(const u16x8*)(Wsrc + (size_t)r * DIM + off);
  }

  for (int kk = 0; kk < DIM; kk += 64) {
    __syncthreads();
#pragma unroll
    for (int it = 0; it < 2; it++) {
      const int c4 = t + it * 256;
      const int r = c4 >> 3, off = (c4 & 7) * 8;
      *(u16x8*)&As[r][off] = pfA[it];
      *(u16x8*)&Bs[r][off] = pfB[it];
    }
    if (kk + 64 < DIM) {
#pragma unroll
      for (int it = 0; it < 2; it++) {
        const int c4 = t + it * 256;
        const int r = c4 >> 3, off = (c4 & 7) * 8;
        pfA[it] = *(const u16x8*)(A + (size_t)(m0 + r) * DIM + kk + 64 + off);
        pfB[it] = *(const u16x8*)(Wsrc + (size_t)r * DIM + kk + 64 + off);
      }
    }
    __syncthreads();
#pragma unroll
    for (int kx = 0; kx < 2; kx++) {
      bf16x8 af[2], bfr[2];
#pragma unroll
      for (int i = 0; i < 2; i++)
        af[i] = *(const bf16x8*)&As[wm * 32 + i * 16 + l15][kx * 32 + quad * 8];
#pragma unroll
      for (int j = 0; j < 2; j++)
        bfr[j] = *(const bf16x8*)&Bs[wn * 32 + j * 16 + l15][kx * 32 + quad * 8];
#pragma unroll
      for (int i = 0; i < 2; i++)
#pragma unroll
        for (int j = 0; j < 2; j++)
          acc[i][j] = __builtin_amdgcn_mfma_f32_16x16x32_bf16(
              af[i], bfr[j], acc[i][j], 0, 0, 0);
    }
  }

#pragma unroll
  for (int i = 0; i < 2; i++) {
    const int m = m0 + wm * 32 + i * 16 + quad * 4;
#pragma unroll
    for (int j = 0; j < 2; j++) {
      const int n = n0 + wn * 32 + j * 16 + l15;
#pragma unroll
      for (int r = 0; r < 4; r++)
        Co[(size_t)(m + r) * DIM + n] = acc[i][j][r];
    }
  }
}

// ---------------------------------------------------------------------------
extern "C" void kernel_launch(void* const* d_in, const int* in_sizes, int n_in,
                              void* d_out, int out_size, void* d_ws,
                              size_t ws_size, hipStream_t stream)
{
  const float* x     = (const float*)d_in[0];
  const float* gamma = (const float*)d_in[1];
  const float* beta  = (const float*)d_in[2];
  const float* wq    = (const float*)d_in[3];
  const float* wk    = (const float*)d_in[4];
  const float* wv    = (const float*)d_in[5];
  const float* wfc   = (const float*)d_in[6];
  float* out = (float*)d_out;

  char* ws = (char*)d_ws;
  u16* Qb = (u16*)(ws);                       //  8 MB [b,h,s,d] (pre-scaled)
  u16* Kb = (u16*)(ws + ((size_t)8  << 20));  //  8 MB [b,h,s,d]
  u16* Vt = (u16*)(ws + ((size_t)16 << 20));  //  8 MB [b,h,d,s]
  u16* Ob = (u16*)(ws + ((size_t)24 << 20));  //  8 MB [b,s,h*64+d]
  u16* Wb = (u16*)(ws + ((size_t)32 << 20));  //  2 MB bf16 weights
  u16* xn = (u16*)(ws + ((size_t)34 << 20));  //  8 MB [8192][512] bf16

  prep_kernel<<<2560, 256, 0, stream>>>(x, gamma, beta, wq, wk, wv, wfc,
                                        Wb, xn);
  gemm_qkv_kernel<<<dim3(12, 64), 256, 0, stream>>>(xn, Wb, Qb, Kb, Vt);
  attn_kernel<<<1024, 256, 0, stream>>>(Qb, Kb, Vt, Ob);
  gemm_fc_kernel<<<dim3(8, 128), 256, 0, stream>>>(Ob, Wb, out);
}